// Round 15
// baseline (296.953 us; speedup 1.0000x reference)
//
#include <hip/hip_runtime.h>
#include <hip/hip_bf16.h>
#include <cstdint>
#include <cstddef>

#define NB 4096     // batch rows
#define NC 1000     // real classes
#define NCP 1024    // padded classes
#define ND 3072     // feature dim
#define NSL 8       // split-K slices -> grid 512 = 2 blocks/CU
#define KSL (ND / NSL)   // 384
#define BM 256
#define BN 256
#define BK 32
#define NT (KSL / BK)    // 12 K-steps per slice
#define ABUF (BM * BK)   // 8192 elems (16 KiB bf16)
#define BBUF (BN * BK)

typedef __attribute__((ext_vector_type(8))) __bf16 bf16x8;
typedef __attribute__((ext_vector_type(4))) float f32x4;
typedef __attribute__((ext_vector_type(4))) unsigned short u16x4;
typedef __attribute__((ext_vector_type(4))) _Float16 f16x4;
typedef unsigned short u16;

__device__ __forceinline__ u16 f2bf_rne(float x) {
    uint32_t u = __float_as_uint(x);
    uint32_t r = (u + 0x7fffu + ((u >> 16) & 1u)) >> 16;
    return (u16)r;
}

// ---------------------------------------------------------------------------
// Fused convert: blocks [0,NB) convert z rows (z2 = ||z||^2); blocks
// [NB, NB+NCP) convert means rows (rows >= NC zero-padded, m2 = 1e30 kills
// padded classes in the LSE).
// ---------------------------------------------------------------------------
__global__ __launch_bounds__(256) void convert_all_kernel(
        const float* __restrict__ z, const float* __restrict__ means,
        u16* __restrict__ zb, u16* __restrict__ mb,
        float* __restrict__ z2, float* __restrict__ m2) {
    const int bidx = blockIdx.x;
    const int tid = threadIdx.x;
    const float* src;
    u16* dst;
    float* sq;
    bool pad = false;
    if (bidx < NB) {
        src = z + (size_t)bidx * ND;
        dst = zb + (size_t)bidx * ND;
        sq = z2 + bidx;
    } else {
        const int mr = bidx - NB;
        dst = mb + (size_t)mr * ND;
        sq = m2 + mr;
        src = means + (size_t)mr * ND;
        pad = (mr >= NC);
    }
    if (!pad) {
        const float4* s = (const float4*)src;
        float acc = 0.f;
#pragma unroll
        for (int i = 0; i < 3; ++i) {                // 768 float4 / 256 threads
            const int idx = tid + i * 256;
            float4 v = s[idx];
            acc = fmaf(v.x, v.x, acc);
            acc = fmaf(v.y, v.y, acc);
            acc = fmaf(v.z, v.z, acc);
            acc = fmaf(v.w, v.w, acc);
            u16x4 o;
            o.x = f2bf_rne(v.x); o.y = f2bf_rne(v.y);
            o.z = f2bf_rne(v.z); o.w = f2bf_rne(v.w);
            *(u16x4*)(dst + idx * 4) = o;
        }
#pragma unroll
        for (int off = 32; off > 0; off >>= 1) acc += __shfl_xor(acc, off, 64);
        __shared__ float ssum[4];
        const int wid = tid >> 6, lane = tid & 63;
        if (lane == 0) ssum[wid] = acc;
        __syncthreads();
        if (tid == 0) sq[0] = ssum[0] + ssum[1] + ssum[2] + ssum[3];
    } else {
        u16x4 z4 = (u16x4){0, 0, 0, 0};
#pragma unroll
        for (int i = 0; i < 3; ++i) *(u16x4*)(dst + (tid + i * 256) * 4) = z4;
        if (tid == 0) sq[0] = 1e30f;
    }
}

// ---------------------------------------------------------------------------
// crossh[s][b][c] = (f16) sum over K-slice s of z_b . mu_c  (raw partials).
// {256x256 tile, 2 blocks/CU} grid cell: NSL=8 -> grid 512, 2 LDS buffers
// (64 KiB/block -> 2 blocks fit 160 KiB), R6-verified vmcnt(0) + single
// raw-barrier loop (sibling block hides the drain — m114 mechanism; counted
// depth>1 is provably racy with 2 buffers). Staged bytes stay 201 MB
// (restage factor is NSL-independent). XCD map: 64 consecutive w per XCD =
// one full K-slice -> slice A (3 MB) + B (0.75 MB) fits 4 MB XCD L2.
// launch_bounds(1024,8) caps VGPR at 64 (R10 measured exactly 64) so both
// blocks co-reside. T2 XOR swizzle (0-conflict verified R6/R9/R10).
// ---------------------------------------------------------------------------
#define GLOAD_LDS16(gp, lp)                                            \
    __builtin_amdgcn_global_load_lds(                                  \
        (const __attribute__((address_space(1))) void*)(gp),           \
        (__attribute__((address_space(3))) void*)(lp), 16, 0, 0)

__global__ __launch_bounds__(1024, 8) void gemm_kernel(
        const u16* __restrict__ zb, const u16* __restrict__ mb,
        _Float16* __restrict__ crossh) {
    __shared__ u16 As[2 * ABUF];   // 32 KiB (2 buffers)
    __shared__ u16 Bs[2 * BBUF];   // 32 KiB

    const int tid  = threadIdx.x;
    const int wid  = tid >> 6;
    const int lane = tid & 63;
    const int wrr  = (wid >> 2) * 64;    // wave row offset (0..192)
    const int wcc  = (wid & 3) * 64;     // wave col offset (0..192)
    const int lrow = lane & 15;          // fragment row index
    const int kgrp = lane >> 4;          // k-group 0..3

    // XCD-chunked work: 64 consecutive w per XCD = one full K-slice.
    const int bid = blockIdx.x;
    const int w = (bid & 7) * 64 + (bid >> 3);
    const int ksl  = w >> 6;             // 0..7
    const int rem  = w & 63;
    const int brow = (rem >> 2) * BM;    // 16 row panels
    const int bcol = (rem & 3) * BN;     // 4 col panels
    const int kbase = ksl * KSL;

    f32x4 acc[4][4];
#pragma unroll
    for (int m = 0; m < 4; ++m)
#pragma unroll
        for (int n = 0; n < 4; ++n) acc[m][n] = (f32x4){0.f, 0.f, 0.f, 0.f};

    // Staging: chunk c = tid (16B) -> row r = c>>2, phys slot p = c&3.
    // Physical slot p holds global k-slot s = p ^ ((r>>1)&3) (XOR involution,
    // DMA-linear dest; verified 0 bank conflicts).
    const u16* gA;
    const u16* gB;
    u16* lA;
    u16* lB;
    {
        const int r = tid >> 2, p = tid & 3, s = p ^ ((r >> 1) & 3);
        gA = zb + (size_t)(brow + r) * ND + kbase + s * 8;
        gB = mb + (size_t)(bcol + r) * ND + kbase + s * 8;
        lA = As + wid * 512;     // wave-uniform base (buf 0): 64 chunks/wave
        lB = Bs + wid * 512;
    }

#define STAGE(tt) do {                                                   \
        const int bb_ = (tt) & 1;                                        \
        const int ko_ = (tt) * BK;                                       \
        GLOAD_LDS16(gA + ko_, lA + bb_ * ABUF);                          \
        GLOAD_LDS16(gB + ko_, lB + bb_ * BBUF);                          \
    } while (0)

#define COMP(tt) do {                                                    \
        const int cb_ = (tt) & 1;                                        \
        const u16* Ac = As + cb_ * ABUF;                                 \
        const u16* Bc = Bs + cb_ * BBUF;                                 \
        const int pk = kgrp ^ ((lrow >> 1) & 3);                         \
        bf16x8 a0 = *(const bf16x8*)&Ac[(wrr +  0 + lrow) * BK + pk * 8]; \
        bf16x8 a1 = *(const bf16x8*)&Ac[(wrr + 16 + lrow) * BK + pk * 8]; \
        bf16x8 a2 = *(const bf16x8*)&Ac[(wrr + 32 + lrow) * BK + pk * 8]; \
        bf16x8 a3 = *(const bf16x8*)&Ac[(wrr + 48 + lrow) * BK + pk * 8]; \
        _Pragma("unroll")                                                \
        for (int n = 0; n < 4; ++n) {                                    \
            bf16x8 bn = *(const bf16x8*)&Bc[(wcc + n * 16 + lrow) * BK + pk * 8]; \
            acc[0][n] = __builtin_amdgcn_mfma_f32_16x16x32_bf16(a0, bn, acc[0][n], 0, 0, 0); \
            acc[1][n] = __builtin_amdgcn_mfma_f32_16x16x32_bf16(a1, bn, acc[1][n], 0, 0, 0); \
            acc[2][n] = __builtin_amdgcn_mfma_f32_16x16x32_bf16(a2, bn, acc[2][n], 0, 0, 0); \
            acc[3][n] = __builtin_amdgcn_mfma_f32_16x16x32_bf16(a3, bn, acc[3][n], 0, 0, 0); \
        }                                                                \
    } while (0)

    // prologue: stage tile 0 into buffer 0
    STAGE(0);

    for (int t = 0; t < NT; ++t) {
        asm volatile("s_waitcnt vmcnt(0)" ::: "memory");  // tile t landed
        __builtin_amdgcn_s_barrier();      // tile t visible; buf (t+1)&1's
                                           // readers (COMP(t-1)) all done
        __builtin_amdgcn_sched_barrier(0);
        if (t + 1 < NT) STAGE(t + 1);      // overlaps COMP(t); drain hidden
        __builtin_amdgcn_sched_barrier(0); // by the sibling block on this CU
        COMP(t);
    }

#undef STAGE
#undef COMP

    // epilogue: C/D layout col = lane&15, row = (lane>>4)*4 + r  (f16 partial)
    _Float16* outp = crossh + (size_t)ksl * NB * NCP;
#pragma unroll
    for (int n = 0; n < 4; ++n) {
        const int gcol = bcol + wcc + n * 16 + lrow;
#pragma unroll
        for (int m = 0; m < 4; ++m) {
#pragma unroll
            for (int r = 0; r < 4; ++r) {
                const int grow = brow + wrr + m * 16 + kgrp * 4 + r;
                outp[(size_t)grow * NCP + gcol] = (_Float16)acc[m][n][r];
            }
        }
    }
}

// ---------------------------------------------------------------------------
// Per-row: d'[c] = sum_s crossh[s][b][c] - 0.5*m2[c].  z^2 cancels exactly in
// loss_cls (outA = LSE(d') - d'[label]); its mean is applied in finalize for
// loss_gen.  outB = LSE(d') + sldj[b].
// ---------------------------------------------------------------------------
__global__ __launch_bounds__(256) void row_lse_kernel(
        const _Float16* __restrict__ crossh, const float* __restrict__ m2,
        const int* __restrict__ labels, const float* __restrict__ sldj,
        float* __restrict__ outA, float* __restrict__ outB) {
    const int row = blockIdx.x;
    const int tid = threadIdx.x;

    float a0 = 0.f, a1 = 0.f, a2 = 0.f, a3 = 0.f;
#pragma unroll
    for (int s = 0; s < NSL; ++s) {
        f16x4 h = ((const f16x4*)(crossh + ((size_t)s * NB + row) * NCP))[tid];
        a0 += (float)h.x; a1 += (float)h.y; a2 += (float)h.z; a3 += (float)h.w;
    }
    float4 mm = ((const float4*)m2)[tid];
    float4 v;
    v.x = a0 - 0.5f * mm.x;
    v.y = a1 - 0.5f * mm.y;
    v.z = a2 - 0.5f * mm.z;
    v.w = a3 - 0.5f * mm.w;

    float mx = fmaxf(fmaxf(v.x, v.y), fmaxf(v.z, v.w));
#pragma unroll
    for (int off = 32; off > 0; off >>= 1) mx = fmaxf(mx, __shfl_xor(mx, off, 64));
    __shared__ float smax[4], ssum[4];
    const int wid = tid >> 6, lane = tid & 63;
    if (lane == 0) smax[wid] = mx;
    __syncthreads();
    const float bm = fmaxf(fmaxf(smax[0], smax[1]), fmaxf(smax[2], smax[3]));

    float s = expf(v.x - bm) + expf(v.y - bm) + expf(v.z - bm) + expf(v.w - bm);
#pragma unroll
    for (int off = 32; off > 0; off >>= 1) s += __shfl_xor(s, off, 64);
    if (lane == 0) ssum[wid] = s;
    __syncthreads();
    if (tid == 0) {
        const float tot = ssum[0] + ssum[1] + ssum[2] + ssum[3];
        const float lpz = bm + logf(tot);
        const int lab = labels[row];
        float pick = 0.f;
#pragma unroll
        for (int si = 0; si < NSL; ++si)
            pick += (float)crossh[((size_t)si * NB + row) * NCP + lab];
        pick -= 0.5f * m2[lab];
        outA[row] = lpz - pick;
        outB[row] = lpz + sldj[row];
    }
}

// ---------------------------------------------------------------------------
// Deterministic final reduction. loss_cls = mean(outA);
// mean(log_pz + sldj) = mean(outB) - 0.5*mean(z2);  loss_gen = -that/ND.
// ---------------------------------------------------------------------------
__global__ __launch_bounds__(1024) void finalize_kernel(
        const float* __restrict__ a, const float* __restrict__ b,
        const float* __restrict__ z2, const float* __restrict__ beta,
        float* __restrict__ out) {
    __shared__ float sa[1024], sb[1024], sz[1024];
    const int tid = threadIdx.x;
    float va = 0.f, vb = 0.f, vz = 0.f;
    for (int i = tid; i < NB; i += 1024) {
        va += a[i]; vb += b[i]; vz += z2[i];
    }
    sa[tid] = va; sb[tid] = vb; sz[tid] = vz;
    __syncthreads();
    for (int s = 512; s > 0; s >>= 1) {
        if (tid < s) {
            sa[tid] += sa[tid + s];
            sb[tid] += sb[tid + s];
            sz[tid] += sz[tid + s];
        }
        __syncthreads();
    }
    if (tid == 0) {
        const float loss_cls = sa[0] / (float)NB;
        const float mean_lpz_sldj = sb[0] / (float)NB - 0.5f * (sz[0] / (float)NB);
        const float loss_gen = -mean_lpz_sldj / (float)ND;
        const float total = loss_gen + beta[0] * loss_cls;
        out[0] = total;
        out[1] = loss_gen;
        out[2] = loss_cls;
    }
}

extern "C" void kernel_launch(void* const* d_in, const int* in_sizes, int n_in,
                              void* d_out, int out_size, void* d_ws, size_t ws_size,
                              hipStream_t stream) {
    const float* z      = (const float*)d_in[0];
    const float* sldj   = (const float*)d_in[1];
    const int*   labels = (const int*)d_in[2];
    const float* beta   = (const float*)d_in[3];
    const float* means  = (const float*)d_in[4];
    float* out = (float*)d_out;

    char* ws = (char*)d_ws;
    size_t off = 0;
    u16* zb = (u16*)(ws + off);           off += (size_t)NB * ND * 2;          // 25.2 MB
    u16* mb = (u16*)(ws + off);           off += (size_t)NCP * ND * 2;         //  6.3 MB
    float* z2 = (float*)(ws + off);       off += (size_t)NB * 4;
    float* m2 = (float*)(ws + off);       off += (size_t)NCP * 4;
    _Float16* crossh = (_Float16*)(ws + off); off += (size_t)NSL * NB * NCP * 2; // 67.1 MB
    float* ra = (float*)(ws + off);       off += (size_t)NB * 4;
    float* rb = (float*)(ws + off);       off += (size_t)NB * 4;
    // total ~99 MB; ws_size = 256 MiB (observed via harness 0x10000000 fill)

    convert_all_kernel<<<NB + NCP, 256, 0, stream>>>(z, means, zb, mb, z2, m2);
    gemm_kernel<<<4 * 16 * NSL, 1024, 0, stream>>>(zb, mb, crossh);
    row_lse_kernel<<<NB, 256, 0, stream>>>(crossh, m2, labels, sldj, ra, rb);
    finalize_kernel<<<1, 1024, 0, stream>>>(ra, rb, z2, beta, out);
}

// Round 16
// 60.440 us; speedup vs baseline: 4.9132x; 4.9132x over previous
//
#include <hip/hip_runtime.h>
#include <hip/hip_bf16.h>
#include <cstdint>
#include <cstddef>

#define NB 4096     // batch rows
#define NC 1000     // real classes
#define NCP 1024    // padded classes
#define ND 3072     // feature dim
#define NSL 4       // split-K slices
#define KSL (ND / NSL)   // 768
#define BM 256
#define BN 256
#define BK 32
#define NT (KSL / BK)    // 24 K-steps per slice
#define ABUF (BM * BK)   // 8192 elems (16 KiB bf16)
#define BBUF (BN * BK)

typedef __attribute__((ext_vector_type(8))) __bf16 bf16x8;
typedef __attribute__((ext_vector_type(4))) float f32x4;
typedef __attribute__((ext_vector_type(4))) unsigned short u16x4;
typedef __attribute__((ext_vector_type(4))) _Float16 f16x4;
typedef unsigned short u16;

__device__ __forceinline__ u16 f2bf_rne(float x) {
    uint32_t u = __float_as_uint(x);
    uint32_t r = (u + 0x7fffu + ((u >> 16) & 1u)) >> 16;
    return (u16)r;
}

// ---------------------------------------------------------------------------
// Fused convert: blocks [0,NB) convert z rows (z2 = ||z||^2); blocks
// [NB, NB+NCP) convert means rows (rows >= NC zero-padded, m2 = 1e30 kills
// padded classes in the LSE).
// ---------------------------------------------------------------------------
__global__ __launch_bounds__(256) void convert_all_kernel(
        const float* __restrict__ z, const float* __restrict__ means,
        u16* __restrict__ zb, u16* __restrict__ mb,
        float* __restrict__ z2, float* __restrict__ m2) {
    const int bidx = blockIdx.x;
    const int tid = threadIdx.x;
    const float* src;
    u16* dst;
    float* sq;
    bool pad = false;
    if (bidx < NB) {
        src = z + (size_t)bidx * ND;
        dst = zb + (size_t)bidx * ND;
        sq = z2 + bidx;
    } else {
        const int mr = bidx - NB;
        dst = mb + (size_t)mr * ND;
        sq = m2 + mr;
        src = means + (size_t)mr * ND;
        pad = (mr >= NC);
    }
    if (!pad) {
        const float4* s = (const float4*)src;
        float acc = 0.f;
#pragma unroll
        for (int i = 0; i < 3; ++i) {                // 768 float4 / 256 threads
            const int idx = tid + i * 256;
            float4 v = s[idx];
            acc = fmaf(v.x, v.x, acc);
            acc = fmaf(v.y, v.y, acc);
            acc = fmaf(v.z, v.z, acc);
            acc = fmaf(v.w, v.w, acc);
            u16x4 o;
            o.x = f2bf_rne(v.x); o.y = f2bf_rne(v.y);
            o.z = f2bf_rne(v.z); o.w = f2bf_rne(v.w);
            *(u16x4*)(dst + idx * 4) = o;
        }
#pragma unroll
        for (int off = 32; off > 0; off >>= 1) acc += __shfl_xor(acc, off, 64);
        __shared__ float ssum[4];
        const int wid = tid >> 6, lane = tid & 63;
        if (lane == 0) ssum[wid] = acc;
        __syncthreads();
        if (tid == 0) sq[0] = ssum[0] + ssum[1] + ssum[2] + ssum[3];
    } else {
        u16x4 z4 = (u16x4){0, 0, 0, 0};
#pragma unroll
        for (int i = 0; i < 3; ++i) *(u16x4*)(dst + (tid + i * 256) * 4) = z4;
        if (tid == 0) sq[0] = 1e30f;
    }
}

// ---------------------------------------------------------------------------
// crossh[s][b][c] = (f16) sum over K-slice s of z_b . mu_c  (raw partials).
// BEST-MEASURED CONFIG (60.18/60.44 us total, reproduced twice): 256x256
// tile (staged bytes 201 MB), 16 waves (1024 thr, 4x4 grid of the verified
// 64x64 wave tile), BK=32, 4 LDS buffers (128 KiB), depth-3 counted-vmcnt
// pipeline (vmcnt 4/2/0), one raw s_barrier per K-step. NSL=4 -> grid 256.
// T2 XOR swizzle: phys slot p holds k-slot s = p ^ ((r>>1)&3) (0-conflict
// verified). Neighbors all measured worse or infeasible:
//   128x128 tiles (2-4 blk/CU): 43-45 us  [R6/R9 — 2x staged bytes]
//   8 waves / 128x64 wave tile: regression [R11 — TLP halved]
//   depth-4 + setprio:          regression [R12 — lockstep, T5 null regime]
//   8-phase m201 port:          regression [R13 — only 5 steady iters]
//   2 blocks/CU (launch_bounds(1024,8)): INFEASIBLE — 32-VGPR cap spills
//     the 64-reg accumulator to scratch (R15: VGPR=32, 888 MB writes, 268us)
// ---------------------------------------------------------------------------
#define GLOAD_LDS16(gp, lp)                                            \
    __builtin_amdgcn_global_load_lds(                                  \
        (const __attribute__((address_space(1))) void*)(gp),           \
        (__attribute__((address_space(3))) void*)(lp), 16, 0, 0)

__global__ __launch_bounds__(1024, 4) void gemm_kernel(
        const u16* __restrict__ zb, const u16* __restrict__ mb,
        _Float16* __restrict__ crossh) {
    __shared__ u16 As[4 * ABUF];   // 64 KiB (4 buffers)
    __shared__ u16 Bs[4 * BBUF];   // 64 KiB

    const int tid  = threadIdx.x;
    const int wid  = tid >> 6;
    const int lane = tid & 63;
    const int wrr  = (wid >> 2) * 64;    // wave row offset (0..192)
    const int wcc  = (wid & 3) * 64;     // wave col offset (0..192)
    const int lrow = lane & 15;          // fragment row index
    const int kgrp = lane >> 4;          // k-group 0..3

    // XCD-chunked work: 32 consecutive w per XCD (half a K-slice: 8 brows x
    // 4 bcols share panels within one XCD's L2).
    const int bid = blockIdx.x;
    const int w = (bid & 7) * 32 + (bid >> 3);
    const int ksl  = w >> 6;
    const int rem  = w & 63;
    const int brow = (rem >> 2) * BM;
    const int bcol = (rem & 3) * BN;
    const int kbase = ksl * KSL;

    f32x4 acc[4][4];
#pragma unroll
    for (int m = 0; m < 4; ++m)
#pragma unroll
        for (int n = 0; n < 4; ++n) acc[m][n] = (f32x4){0.f, 0.f, 0.f, 0.f};

    // Staging: chunk c = tid (16B) -> row r = c>>2, phys slot p = c&3.
    // Physical slot p holds global k-slot s = p ^ ((r>>1)&3) (XOR involution,
    // DMA-linear dest; verified 0 bank conflicts).
    const u16* gA;
    const u16* gB;
    u16* lA;
    u16* lB;
    {
        const int r = tid >> 2, p = tid & 3, s = p ^ ((r >> 1) & 3);
        gA = zb + (size_t)(brow + r) * ND + kbase + s * 8;
        gB = mb + (size_t)(bcol + r) * ND + kbase + s * 8;
        lA = As + wid * 512;     // wave-uniform base (buf 0): 64 chunks/wave
        lB = Bs + wid * 512;
    }

#define STAGE(tt) do {                                                   \
        const int bb_ = (tt) & 3;                                        \
        const int ko_ = (tt) * BK;                                       \
        GLOAD_LDS16(gA + ko_, lA + bb_ * ABUF);                          \
        GLOAD_LDS16(gB + ko_, lB + bb_ * BBUF);                          \
    } while (0)

#define COMP(tt) do {                                                    \
        const int cb_ = (tt) & 3;                                        \
        const u16* Ac = As + cb_ * ABUF;                                 \
        const u16* Bc = Bs + cb_ * BBUF;                                 \
        const int pk = kgrp ^ ((lrow >> 1) & 3);                         \
        bf16x8 a0 = *(const bf16x8*)&Ac[(wrr +  0 + lrow) * BK + pk * 8]; \
        bf16x8 a1 = *(const bf16x8*)&Ac[(wrr + 16 + lrow) * BK + pk * 8]; \
        bf16x8 a2 = *(const bf16x8*)&Ac[(wrr + 32 + lrow) * BK + pk * 8]; \
        bf16x8 a3 = *(const bf16x8*)&Ac[(wrr + 48 + lrow) * BK + pk * 8]; \
        _Pragma("unroll")                                                \
        for (int n = 0; n < 4; ++n) {                                    \
            bf16x8 bn = *(const bf16x8*)&Bc[(wcc + n * 16 + lrow) * BK + pk * 8]; \
            acc[0][n] = __builtin_amdgcn_mfma_f32_16x16x32_bf16(a0, bn, acc[0][n], 0, 0, 0); \
            acc[1][n] = __builtin_amdgcn_mfma_f32_16x16x32_bf16(a1, bn, acc[1][n], 0, 0, 0); \
            acc[2][n] = __builtin_amdgcn_mfma_f32_16x16x32_bf16(a2, bn, acc[2][n], 0, 0, 0); \
            acc[3][n] = __builtin_amdgcn_mfma_f32_16x16x32_bf16(a3, bn, acc[3][n], 0, 0, 0); \
        }                                                                \
    } while (0)

    // prologue: stage tiles 0,1,2 into buffers 0,1,2 (6 loads/thread in flight)
    STAGE(0); STAGE(1); STAGE(2);

    // main loop: counted vmcnt — tiles t+1, t+2 stay in flight across barrier
    for (int t = 0; t < NT - 2; ++t) {
        asm volatile("s_waitcnt vmcnt(4)" ::: "memory");   // tile t landed
        __builtin_amdgcn_s_barrier();      // tile t visible; buf (t+3)&3 free
        __builtin_amdgcn_sched_barrier(0);
        if (t + 3 < NT) STAGE(t + 3);
        __builtin_amdgcn_sched_barrier(0);
        COMP(t);
    }
    // tail: t = NT-2, NT-1
    asm volatile("s_waitcnt vmcnt(2)" ::: "memory");
    __builtin_amdgcn_s_barrier();
    __builtin_amdgcn_sched_barrier(0);
    COMP(NT - 2);
    asm volatile("s_waitcnt vmcnt(0)" ::: "memory");
    __builtin_amdgcn_s_barrier();
    __builtin_amdgcn_sched_barrier(0);
    COMP(NT - 1);

#undef STAGE
#undef COMP

    // epilogue: C/D layout col = lane&15, row = (lane>>4)*4 + r  (f16 partial)
    _Float16* outp = crossh + (size_t)ksl * NB * NCP;
#pragma unroll
    for (int n = 0; n < 4; ++n) {
        const int gcol = bcol + wcc + n * 16 + lrow;
#pragma unroll
        for (int m = 0; m < 4; ++m) {
#pragma unroll
            for (int r = 0; r < 4; ++r) {
                const int grow = brow + wrr + m * 16 + kgrp * 4 + r;
                outp[(size_t)grow * NCP + gcol] = (_Float16)acc[m][n][r];
            }
        }
    }
}

// ---------------------------------------------------------------------------
// Per-row: d'[c] = sum_s crossh[s][b][c] - 0.5*m2[c].  z^2 cancels exactly in
// loss_cls (outA = LSE(d') - d'[label]); its mean is applied in finalize for
// loss_gen.  outB = LSE(d') + sldj[b].
// ---------------------------------------------------------------------------
__global__ __launch_bounds__(256) void row_lse_kernel(
        const _Float16* __restrict__ crossh, const float* __restrict__ m2,
        const int* __restrict__ labels, const float* __restrict__ sldj,
        float* __restrict__ outA, float* __restrict__ outB) {
    const int row = blockIdx.x;
    const int tid = threadIdx.x;

    float a0 = 0.f, a1 = 0.f, a2 = 0.f, a3 = 0.f;
#pragma unroll
    for (int s = 0; s < NSL; ++s) {
        f16x4 h = ((const f16x4*)(crossh + ((size_t)s * NB + row) * NCP))[tid];
        a0 += (float)h.x; a1 += (float)h.y; a2 += (float)h.z; a3 += (float)h.w;
    }
    float4 mm = ((const float4*)m2)[tid];
    float4 v;
    v.x = a0 - 0.5f * mm.x;
    v.y = a1 - 0.5f * mm.y;
    v.z = a2 - 0.5f * mm.z;
    v.w = a3 - 0.5f * mm.w;

    float mx = fmaxf(fmaxf(v.x, v.y), fmaxf(v.z, v.w));
#pragma unroll
    for (int off = 32; off > 0; off >>= 1) mx = fmaxf(mx, __shfl_xor(mx, off, 64));
    __shared__ float smax[4], ssum[4];
    const int wid = tid >> 6, lane = tid & 63;
    if (lane == 0) smax[wid] = mx;
    __syncthreads();
    const float bm = fmaxf(fmaxf(smax[0], smax[1]), fmaxf(smax[2], smax[3]));

    float s = expf(v.x - bm) + expf(v.y - bm) + expf(v.z - bm) + expf(v.w - bm);
#pragma unroll
    for (int off = 32; off > 0; off >>= 1) s += __shfl_xor(s, off, 64);
    if (lane == 0) ssum[wid] = s;
    __syncthreads();
    if (tid == 0) {
        const float tot = ssum[0] + ssum[1] + ssum[2] + ssum[3];
        const float lpz = bm + logf(tot);
        const int lab = labels[row];
        float pick = 0.f;
#pragma unroll
        for (int si = 0; si < NSL; ++si)
            pick += (float)crossh[((size_t)si * NB + row) * NCP + lab];
        pick -= 0.5f * m2[lab];
        outA[row] = lpz - pick;
        outB[row] = lpz + sldj[row];
    }
}

// ---------------------------------------------------------------------------
// Deterministic final reduction. loss_cls = mean(outA);
// mean(log_pz + sldj) = mean(outB) - 0.5*mean(z2);  loss_gen = -that/ND.
// ---------------------------------------------------------------------------
__global__ __launch_bounds__(1024) void finalize_kernel(
        const float* __restrict__ a, const float* __restrict__ b,
        const float* __restrict__ z2, const float* __restrict__ beta,
        float* __restrict__ out) {
    __shared__ float sa[1024], sb[1024], sz[1024];
    const int tid = threadIdx.x;
    float va = 0.f, vb = 0.f, vz = 0.f;
    for (int i = tid; i < NB; i += 1024) {
        va += a[i]; vb += b[i]; vz += z2[i];
    }
    sa[tid] = va; sb[tid] = vb; sz[tid] = vz;
    __syncthreads();
    for (int s = 512; s > 0; s >>= 1) {
        if (tid < s) {
            sa[tid] += sa[tid + s];
            sb[tid] += sb[tid + s];
            sz[tid] += sz[tid + s];
        }
        __syncthreads();
    }
    if (tid == 0) {
        const float loss_cls = sa[0] / (float)NB;
        const float mean_lpz_sldj = sb[0] / (float)NB - 0.5f * (sz[0] / (float)NB);
        const float loss_gen = -mean_lpz_sldj / (float)ND;
        const float total = loss_gen + beta[0] * loss_cls;
        out[0] = total;
        out[1] = loss_gen;
        out[2] = loss_cls;
    }
}

extern "C" void kernel_launch(void* const* d_in, const int* in_sizes, int n_in,
                              void* d_out, int out_size, void* d_ws, size_t ws_size,
                              hipStream_t stream) {
    const float* z      = (const float*)d_in[0];
    const float* sldj   = (const float*)d_in[1];
    const int*   labels = (const int*)d_in[2];
    const float* beta   = (const float*)d_in[3];
    const float* means  = (const float*)d_in[4];
    float* out = (float*)d_out;

    char* ws = (char*)d_ws;
    size_t off = 0;
    u16* zb = (u16*)(ws + off);           off += (size_t)NB * ND * 2;          // 25.2 MB
    u16* mb = (u16*)(ws + off);           off += (size_t)NCP * ND * 2;         //  6.3 MB
    float* z2 = (float*)(ws + off);       off += (size_t)NB * 4;
    float* m2 = (float*)(ws + off);       off += (size_t)NCP * 4;
    _Float16* crossh = (_Float16*)(ws + off); off += (size_t)NSL * NB * NCP * 2; // 33.6 MB
    float* ra = (float*)(ws + off);       off += (size_t)NB * 4;
    float* rb = (float*)(ws + off);       off += (size_t)NB * 4;

    convert_all_kernel<<<NB + NCP, 256, 0, stream>>>(z, means, zb, mb, z2, m2);
    gemm_kernel<<<8 * 32 * NSL / 4, 1024, 0, stream>>>(zb, mb, crossh);
    row_lse_kernel<<<NB, 256, 0, stream>>>(crossh, m2, labels, sldj, ra, rb);
    finalize_kernel<<<1, 1024, 0, stream>>>(ra, rb, z2, beta, out);
}